// Round 6
// baseline (599.292 us; speedup 1.0000x reference)
//
#include <hip/hip_runtime.h>
#include <stdint.h>

// B=4, T=2048, C=1024, H=16, HD=64
// qkb: [B*T][2048] bf16 (Q cols 0..1023, K cols 1024..2047)
// vt : [B][H][64][2048] bf16 (V transposed per head)
// attb: [B*T][1024] bf16

typedef float f32x4 __attribute__((ext_vector_type(4)));
typedef short s16x8 __attribute__((ext_vector_type(8)));
typedef unsigned short u16x4 __attribute__((ext_vector_type(4)));

typedef __attribute__((address_space(1))) const unsigned int gu32;
typedef __attribute__((address_space(3))) unsigned int lu32;

__device__ __forceinline__ unsigned short f2b(float f) {
  unsigned u = __builtin_bit_cast(unsigned, f);
  u += 0x7fffu + ((u >> 16) & 1u);
  return (unsigned short)(u >> 16);
}

__device__ __forceinline__ void gload16(const void* g, void* l) {
  __builtin_amdgcn_global_load_lds((gu32*)g, (lu32*)l, 16, 0, 0);
}

// ---------------- fp32 -> bf16 conversion ----------------
__global__ __launch_bounds__(256) void cvt_kernel(const float* __restrict__ in,
                                                  unsigned short* __restrict__ out,
                                                  int n4) {
  int i = blockIdx.x * 256 + threadIdx.x;
  if (i < n4) {
    float4 v = reinterpret_cast<const float4*>(in)[i];
    ushort4 o;
    o.x = f2b(v.x); o.y = f2b(v.y); o.z = f2b(v.z); o.w = f2b(v.w);
    reinterpret_cast<ushort4*>(out)[i] = o;
  }
}

// ---------------- GEMM: C = A[M][K] * B[N][K]^T ----------------
// OUTMODE 1: QKV split: cols<2048 -> qkb (C0, [M][2048]); cols>=2048 -> vt (C1, [B][H][64][2048])
// OUTMODE 2: f32 + bias -> C0
template <int M, int N, int K, int OUTMODE>
__global__ __launch_bounds__(256) void gemm_bt(const unsigned short* __restrict__ A,
                                               const unsigned short* __restrict__ B,
                                               const float* __restrict__ bias,
                                               void* __restrict__ C0,
                                               void* __restrict__ C1) {
  __shared__ __align__(16) unsigned short As[128 * 64];
  __shared__ __align__(16) unsigned short Bs[128 * 64];
  const int tid = threadIdx.x;
  const int l = tid & 63, w = tid >> 6;
  const int l15 = l & 15, lq = l >> 4;
  const int wr = w >> 1, wc = w & 1;
  const int m0 = blockIdx.y * 128, n0 = blockIdx.x * 128;
  f32x4 acc[4][4] = {};
  for (int k0 = 0; k0 < K; k0 += 64) {
    __syncthreads();
#pragma unroll
    for (int i = 0; i < 4; i++) {
      int idx = i * 256 + tid;
      gload16(A + (size_t)(m0 + (idx >> 3)) * K + k0 + (idx & 7) * 8, &As[idx * 8]);
    }
#pragma unroll
    for (int i = 0; i < 4; i++) {
      int idx = i * 256 + tid;
      gload16(B + (size_t)(n0 + (idx >> 3)) * K + k0 + (idx & 7) * 8, &Bs[idx * 8]);
    }
    __syncthreads();
#pragma unroll
    for (int kk = 0; kk < 2; kk++) {
      s16x8 af[4], bfv[4];
#pragma unroll
      for (int m = 0; m < 4; m++)
        af[m] = *(const s16x8*)&As[(wr * 64 + m * 16 + l15) * 64 + kk * 32 + lq * 8];
#pragma unroll
      for (int n = 0; n < 4; n++)
        bfv[n] = *(const s16x8*)&Bs[(wc * 64 + n * 16 + l15) * 64 + kk * 32 + lq * 8];
#pragma unroll
      for (int m = 0; m < 4; m++)
#pragma unroll
        for (int n = 0; n < 4; n++)
          acc[m][n] = __builtin_amdgcn_mfma_f32_16x16x32_bf16(af[m], bfv[n], acc[m][n], 0, 0, 0);
    }
  }
  if (OUTMODE == 1 && n0 >= 2048) {
    // V columns: write transposed into vt[b][h][d][q], pack 4 q (r=0..3) per store
    unsigned short* vt = (unsigned short*)C1;
#pragma unroll
    for (int m = 0; m < 4; m++)
#pragma unroll
      for (int n = 0; n < 4; n++) {
        int row0 = m0 + wr * 64 + m * 16 + lq * 4;  // q base (mult of 4)
        int vcol = n0 - 2048 + wc * 64 + n * 16 + l15;  // h*64+d
        int bb = row0 >> 11, q = row0 & 2047;
        u16x4 o;
#pragma unroll
        for (int r = 0; r < 4; r++) o[r] = f2b(acc[m][n][r]);
        *(u16x4*)&vt[((size_t)(bb * 16 + (vcol >> 6)) * 64 + (vcol & 63)) * 2048 + q] = o;
      }
  } else {
#pragma unroll
    for (int m = 0; m < 4; m++)
#pragma unroll
      for (int n = 0; n < 4; n++)
#pragma unroll
        for (int r = 0; r < 4; r++) {
          int row = m0 + wr * 64 + m * 16 + lq * 4 + r;
          int col = n0 + wc * 64 + n * 16 + l15;
          float v = acc[m][n][r];
          if (OUTMODE == 2) {
            ((float*)C0)[(size_t)row * N + col] = v + bias[col];
          } else if (OUTMODE == 1) {
            ((unsigned short*)C0)[(size_t)row * 2048 + col] = f2b(v);
          } else {
            ((unsigned short*)C0)[(size_t)row * N + col] = f2b(v);
          }
        }
  }
}

// ---------------- Flash attention (causal), 8-wave blocks ----------------
// 1 block = (b, h, pair pi): q-groups gA=7-pi then gB=pi (256 rows each).
// Every block: 36 KV tiles. Grid 256 = 1 block/CU. 8 waves x 32 q rows.
// KV tiles of 64, double-buffered; XOR-swizzle byte^=((row&7)<<4).
// Row-sum via MFMA with ones-B (no shuffle sum-reduce).
__global__ __launch_bounds__(512, 4) void attn_kernel(const unsigned short* __restrict__ qkb,
                                                      const unsigned short* __restrict__ vt,
                                                      unsigned short* __restrict__ attb) {
  __shared__ __align__(16) unsigned short Kb[2][64 * 64];
  __shared__ __align__(16) unsigned short Vb[2][64 * 64];
  __shared__ __align__(16) unsigned short Pl[8][32 * 64];
  const int tid = threadIdx.x, l = tid & 63, w = tid >> 6;
  const int l15 = l & 15, lq = l >> 4;
  const int bid = blockIdx.x;
  const int pi = bid & 3;
  const int h = (bid >> 2) & 15, b = bid >> 6;
  const size_t rowbase = (size_t)b * 2048;
  const unsigned short* kbase = qkb + rowbase * 2048 + 1024 + h * 64;
  const unsigned short* vbase = vt + (size_t)(b * 16 + h) * 64 * 2048;
  const int swz = (l15 & 7) << 4;            // read-side XOR (byte units)
  const float c = 0.18033688011112042f;      // 0.125 * log2(e)
  const s16x8 vones = {16256, 16256, 16256, 16256, 16256, 16256, 16256, 16256};  // bf16 1.0

  auto stage = [&](int bs, int t) {
    const int kv0 = t << 6;
    int row = tid >> 3, colb = (tid & 7) << 4;
    int src = colb ^ ((row & 7) << 4);
    gload16(kbase + (size_t)(kv0 + row) * 2048 + (src >> 1), &Kb[bs][tid * 8]);
    gload16(vbase + (size_t)row * 2048 + kv0 + (src >> 1), &Vb[bs][tid * 8]);
  };

  for (int half = 0; half < 2; half++) {
    const int g = half ? pi : 7 - pi;
    const int q0 = g * 256;
    const int nt = 4 * g + 4;
    const int qwmin = q0 + w * 32;

    // Q fragments: qf[m][kk], row = q0+w*32+m*16+l15, k = kk*32+lq*8+j
    s16x8 qf[2][2];
#pragma unroll
    for (int m = 0; m < 2; m++)
#pragma unroll
      for (int kk = 0; kk < 2; kk++)
        qf[m][kk] = *(const s16x8*)&qkb[(rowbase + q0 + w * 32 + m * 16 + l15) * 2048 +
                                        h * 64 + kk * 32 + lq * 8];

    f32x4 oacc[2][4] = {};
    f32x4 lacc[2] = {};
    float mrow[2][4];
#pragma unroll
    for (int m = 0; m < 2; m++)
#pragma unroll
      for (int r = 0; r < 4; r++) mrow[m][r] = -1e30f;

    stage(0, 0);  // previous half's final barrier makes this safe
    __syncthreads();
    int cur = 0;
    for (int t = 0; t < nt; ++t) {
      const int kv0 = t << 6;
      if (t + 1 < nt) stage(cur ^ 1, t + 1);
      if (kv0 <= qwmin + 31) {  // wave has at least one unmasked row
        // ---- S = Q K^T (32 x 64 per wave), raw scores ----
        f32x4 s[2][4];
#pragma unroll
        for (int m = 0; m < 2; m++)
#pragma unroll
          for (int n = 0; n < 4; n++) s[m][n] = (f32x4){0.f, 0.f, 0.f, 0.f};
        __builtin_amdgcn_s_setprio(1);
#pragma unroll
        for (int kk = 0; kk < 2; kk++) {
          s16x8 bk[4];
#pragma unroll
          for (int n = 0; n < 4; n++)
            bk[n] = *(const s16x8*)&Kb[cur][(n * 16 + l15) * 64 +
                                            (((kk * 64 + lq * 16) ^ swz) >> 1)];
#pragma unroll
          for (int m = 0; m < 2; m++)
#pragma unroll
            for (int n = 0; n < 4; n++)
              s[m][n] = __builtin_amdgcn_mfma_f32_16x16x32_bf16(qf[m][kk], bk[n], s[m][n], 0, 0, 0);
        }
        __builtin_amdgcn_s_setprio(0);
        // ---- mask + online max (shuffle); sum comes from MFMA later ----
        const bool needmask = (kv0 + 63) > qwmin;
#pragma unroll
        for (int m = 0; m < 2; m++)
#pragma unroll
          for (int r = 0; r < 4; r++) {
            const int qg = qwmin + m * 16 + lq * 4 + r;
            float mx = -1e30f;
#pragma unroll
            for (int n = 0; n < 4; n++) {
              float v = s[m][n][r];
              if (needmask) v = (kv0 + n * 16 + l15 <= qg) ? v : -1e30f;
              s[m][n][r] = v;
              mx = fmaxf(mx, v);
            }
            mx = fmaxf(mx, __shfl_xor(mx, 1));
            mx = fmaxf(mx, __shfl_xor(mx, 2));
            mx = fmaxf(mx, __shfl_xor(mx, 4));
            mx = fmaxf(mx, __shfl_xor(mx, 8));
            float mn = fmaxf(mrow[m][r], mx);
            float alpha = exp2f((mrow[m][r] - mn) * c);
            mrow[m][r] = mn;
            float mc = mn * c;
#pragma unroll
            for (int n = 0; n < 4; n++)
              s[m][n][r] = exp2f(fmaf(s[m][n][r], c, -mc));
            lacc[m][r] *= alpha;
#pragma unroll
            for (int d = 0; d < 4; d++) oacc[m][d][r] *= alpha;
          }
        // ---- P -> LDS bf16 (swizzled) ----
#pragma unroll
        for (int m = 0; m < 2; m++)
#pragma unroll
          for (int r = 0; r < 4; r++) {
            int row = m * 16 + lq * 4 + r;
            int rx = (row & 7) << 4;
#pragma unroll
            for (int n = 0; n < 4; n++)
              Pl[w][row * 64 + ((((n * 16 + l15) * 2) ^ rx) >> 1)] = f2b(s[m][n][r]);
          }
        // ---- O += P V ; rowsum += P * ones ----
        s16x8 ap[2][2];
#pragma unroll
        for (int m = 0; m < 2; m++)
#pragma unroll
          for (int kk = 0; kk < 2; kk++)
            ap[m][kk] = *(const s16x8*)&Pl[w][(m * 16 + l15) * 64 +
                                              (((kk * 64 + lq * 16) ^ swz) >> 1)];
        __builtin_amdgcn_s_setprio(1);
#pragma unroll
        for (int kk = 0; kk < 2; kk++) {
          s16x8 bv[4];
#pragma unroll
          for (int d = 0; d < 4; d++)
            bv[d] = *(const s16x8*)&Vb[cur][(d * 16 + l15) * 64 +
                                            (((kk * 64 + lq * 16) ^ swz) >> 1)];
#pragma unroll
          for (int m = 0; m < 2; m++) {
#pragma unroll
            for (int d = 0; d < 4; d++)
              oacc[m][d] = __builtin_amdgcn_mfma_f32_16x16x32_bf16(ap[m][kk], bv[d], oacc[m][d], 0, 0, 0);
            lacc[m] = __builtin_amdgcn_mfma_f32_16x16x32_bf16(ap[m][kk], vones, lacc[m], 0, 0, 0);
          }
        }
        __builtin_amdgcn_s_setprio(0);
      }
      __syncthreads();
      cur ^= 1;
    }

    // ---- normalize + store ----
#pragma unroll
    for (int m = 0; m < 2; m++)
#pragma unroll
      for (int d = 0; d < 4; d++) {
        f32x4 o4;
#pragma unroll
        for (int r = 0; r < 4; r++) o4[r] = oacc[m][d][r] / lacc[m][r];
#pragma unroll
        for (int r = 0; r < 4; r++) {
          int qg = q0 + w * 32 + m * 16 + lq * 4 + r;
          attb[(rowbase + qg) * 1024 + h * 64 + d * 16 + l15] = f2b(o4[r]);
        }
      }
  }
}

extern "C" void kernel_launch(void* const* d_in, const int* in_sizes, int n_in,
                              void* d_out, int out_size, void* d_ws, size_t ws_size,
                              hipStream_t stream) {
  const float* x = (const float*)d_in[0];
  const float* wqkv = (const float*)d_in[1];
  const float* wproj = (const float*)d_in[2];
  const float* bproj = (const float*)d_in[3];
  float* out = (float*)d_out;

  unsigned short* xb = (unsigned short*)d_ws;            // 8192*1024
  unsigned short* wqkvb = xb + (size_t)8192 * 1024;      // 3072*1024
  unsigned short* wprojb = wqkvb + (size_t)3072 * 1024;  // 1024*1024
  unsigned short* qkb = wprojb + (size_t)1024 * 1024;    // 8192*2048
  unsigned short* vtb = qkb + (size_t)8192 * 2048;       // 4*16*64*2048
  unsigned short* attb = vtb + (size_t)4 * 16 * 64 * 2048;  // 8192*1024

  cvt_kernel<<<(8192 * 1024 / 4 + 255) / 256, 256, 0, stream>>>(x, xb, 8192 * 1024 / 4);
  cvt_kernel<<<(3072 * 1024 / 4 + 255) / 256, 256, 0, stream>>>(wqkv, wqkvb, 3072 * 1024 / 4);
  cvt_kernel<<<(1024 * 1024 / 4 + 255) / 256, 256, 0, stream>>>(wproj, wprojb, 1024 * 1024 / 4);

  gemm_bt<8192, 3072, 1024, 1>
      <<<dim3(3072 / 128, 8192 / 128), 256, 0, stream>>>(xb, wqkvb, nullptr, qkb, vtb);

  attn_kernel<<<256, 512, 0, stream>>>(qkb, vtb, attb);

  gemm_bt<8192, 1024, 1024, 2>
      <<<dim3(1024 / 128, 8192 / 128), 256, 0, stream>>>(attb, wprojb, bproj, out, nullptr);
}

// Round 7
// 369.406 us; speedup vs baseline: 1.6223x; 1.6223x over previous
//
#include <hip/hip_runtime.h>
#include <stdint.h>

// B=4, T=2048, C=1024, H=16, HD=64
// qkb: [B*T][2048] bf16 (Q cols 0..1023, K cols 1024..2047)
// vt : [B][H][64][2048] bf16 (V transposed per head)
// attb: [B*T][1024] bf16

typedef float f32x4 __attribute__((ext_vector_type(4)));
typedef short s16x8 __attribute__((ext_vector_type(8)));
typedef unsigned short u16x4 __attribute__((ext_vector_type(4)));

typedef __attribute__((address_space(1))) const unsigned int gu32;
typedef __attribute__((address_space(3))) unsigned int lu32;

__device__ __forceinline__ unsigned short f2b(float f) {
  unsigned u = __builtin_bit_cast(unsigned, f);
  u += 0x7fffu + ((u >> 16) & 1u);
  return (unsigned short)(u >> 16);
}

__device__ __forceinline__ void gload16(const void* g, void* l) {
  __builtin_amdgcn_global_load_lds((gu32*)g, (lu32*)l, 16, 0, 0);
}

// ---------------- fp32 -> bf16 conversion ----------------
__global__ __launch_bounds__(256) void cvt_kernel(const float* __restrict__ in,
                                                  unsigned short* __restrict__ out,
                                                  int n4) {
  int i = blockIdx.x * 256 + threadIdx.x;
  if (i < n4) {
    float4 v = reinterpret_cast<const float4*>(in)[i];
    ushort4 o;
    o.x = f2b(v.x); o.y = f2b(v.y); o.z = f2b(v.z); o.w = f2b(v.w);
    reinterpret_cast<ushort4*>(out)[i] = o;
  }
}

// ---------------- GEMM: C = A[M][K] * B[N][K]^T ----------------
// OUTMODE 1: QKV split: cols<2048 -> qkb (C0, [M][2048]); cols>=2048 -> vt (C1, [B][H][64][2048])
// OUTMODE 2: f32 + bias -> C0
template <int M, int N, int K, int OUTMODE>
__global__ __launch_bounds__(256) void gemm_bt(const unsigned short* __restrict__ A,
                                               const unsigned short* __restrict__ B,
                                               const float* __restrict__ bias,
                                               void* __restrict__ C0,
                                               void* __restrict__ C1) {
  __shared__ __align__(16) unsigned short As[128 * 64];
  __shared__ __align__(16) unsigned short Bs[128 * 64];
  const int tid = threadIdx.x;
  const int l = tid & 63, w = tid >> 6;
  const int l15 = l & 15, lq = l >> 4;
  const int wr = w >> 1, wc = w & 1;
  const int m0 = blockIdx.y * 128, n0 = blockIdx.x * 128;
  f32x4 acc[4][4] = {};
  for (int k0 = 0; k0 < K; k0 += 64) {
    __syncthreads();
#pragma unroll
    for (int i = 0; i < 4; i++) {
      int idx = i * 256 + tid;
      gload16(A + (size_t)(m0 + (idx >> 3)) * K + k0 + (idx & 7) * 8, &As[idx * 8]);
    }
#pragma unroll
    for (int i = 0; i < 4; i++) {
      int idx = i * 256 + tid;
      gload16(B + (size_t)(n0 + (idx >> 3)) * K + k0 + (idx & 7) * 8, &Bs[idx * 8]);
    }
    __syncthreads();
#pragma unroll
    for (int kk = 0; kk < 2; kk++) {
      s16x8 af[4], bfv[4];
#pragma unroll
      for (int m = 0; m < 4; m++)
        af[m] = *(const s16x8*)&As[(wr * 64 + m * 16 + l15) * 64 + kk * 32 + lq * 8];
#pragma unroll
      for (int n = 0; n < 4; n++)
        bfv[n] = *(const s16x8*)&Bs[(wc * 64 + n * 16 + l15) * 64 + kk * 32 + lq * 8];
#pragma unroll
      for (int m = 0; m < 4; m++)
#pragma unroll
        for (int n = 0; n < 4; n++)
          acc[m][n] = __builtin_amdgcn_mfma_f32_16x16x32_bf16(af[m], bfv[n], acc[m][n], 0, 0, 0);
    }
  }
  if (OUTMODE == 1 && n0 >= 2048) {
    // V columns: write transposed into vt[b][h][d][q], pack 4 q (r=0..3) per store
    unsigned short* vt = (unsigned short*)C1;
#pragma unroll
    for (int m = 0; m < 4; m++)
#pragma unroll
      for (int n = 0; n < 4; n++) {
        int row0 = m0 + wr * 64 + m * 16 + lq * 4;  // q base (mult of 4)
        int vcol = n0 - 2048 + wc * 64 + n * 16 + l15;  // h*64+d
        int bb = row0 >> 11, q = row0 & 2047;
        u16x4 o;
#pragma unroll
        for (int r = 0; r < 4; r++) o[r] = f2b(acc[m][n][r]);
        *(u16x4*)&vt[((size_t)(bb * 16 + (vcol >> 6)) * 64 + (vcol & 63)) * 2048 + q] = o;
      }
  } else {
#pragma unroll
    for (int m = 0; m < 4; m++)
#pragma unroll
      for (int n = 0; n < 4; n++)
#pragma unroll
        for (int r = 0; r < 4; r++) {
          int row = m0 + wr * 64 + m * 16 + lq * 4 + r;
          int col = n0 + wc * 64 + n * 16 + l15;
          float v = acc[m][n][r];
          if (OUTMODE == 2) {
            ((float*)C0)[(size_t)row * N + col] = v + bias[col];
          } else if (OUTMODE == 1) {
            ((unsigned short*)C0)[(size_t)row * 2048 + col] = f2b(v);
          } else {
            ((unsigned short*)C0)[(size_t)row * N + col] = f2b(v);
          }
        }
  }
}

// ---------------- Flash attention (causal), barrier-free ----------------
// K/V read directly from global (L2-resident per XCD via bijective swizzle).
// 1 block = (b, h, pair pi): q-groups gA=31-pi then gB=pi (64 rows each, 33 tiles total).
// 4 waves x 16 q rows, fully independent: NO __syncthreads anywhere.
// Per-wave P scratch in LDS, XOR-swizzled (byte ^= (row&7)<<4). Rowsum via MFMA-ones.
__global__ __launch_bounds__(256, 4) void attn_kernel(const unsigned short* __restrict__ qkb,
                                                      const unsigned short* __restrict__ vt,
                                                      unsigned short* __restrict__ attb) {
  __shared__ __align__(16) unsigned short Pl[4][16 * 64];  // 8 KB
  const int tid = threadIdx.x, l = tid & 63, w = tid >> 6;
  const int l15 = l & 15, lq = l >> 4;
  // XCD-bijective swizzle: 1024 blocks, 8 XCDs -> each XCD gets 128 consecutive
  // logical ids = 8 heads x 1 batch -> K/V working set 4 MB = its L2.
  const int lbid = (blockIdx.x & 7) * 128 + (blockIdx.x >> 3);
  const int pi = lbid & 15;
  const int h = (lbid >> 4) & 15, b = lbid >> 8;
  const size_t rowbase = (size_t)b * 2048;
  const unsigned short* kbase = qkb + rowbase * 2048 + 1024 + h * 64;
  const unsigned short* vbase = vt + (size_t)(b * 16 + h) * 64 * 2048;
  const int swz = (l15 & 7) << 4;            // read-side XOR (byte units)
  const float c = 0.18033688011112042f;      // 0.125 * log2(e)
  const s16x8 vones = {16256, 16256, 16256, 16256, 16256, 16256, 16256, 16256};  // bf16 1.0

  for (int half = 0; half < 2; half++) {
    const int qb = half ? pi : 31 - pi;      // 64-row q-group index, 0..31
    const int q0 = qb * 64;
    const int qw0 = q0 + w * 16;             // this wave's first q row

    // Q fragments: qf[kk], row = qw0+l15, k = kk*32+lq*8+j
    s16x8 qf[2];
#pragma unroll
    for (int kk = 0; kk < 2; kk++)
      qf[kk] = *(const s16x8*)&qkb[(rowbase + qw0 + l15) * 2048 + h * 64 + kk * 32 + lq * 8];

    f32x4 oacc[4] = {};
    f32x4 lacc = {};
    float mrow[4] = {-1e30f, -1e30f, -1e30f, -1e30f};

    for (int t = 0; t <= qb; ++t) {
      const int kv0 = t << 6;
      // ---- S = Q K^T (16 x 64 per wave), K direct from global ----
      f32x4 s[4];
#pragma unroll
      for (int n = 0; n < 4; n++) s[n] = (f32x4){0.f, 0.f, 0.f, 0.f};
#pragma unroll
      for (int kk = 0; kk < 2; kk++) {
        s16x8 bk[4];
#pragma unroll
        for (int n = 0; n < 4; n++)
          bk[n] = *(const s16x8*)&kbase[(size_t)(kv0 + n * 16 + l15) * 2048 + kk * 32 + lq * 8];
        __builtin_amdgcn_s_setprio(1);
#pragma unroll
        for (int n = 0; n < 4; n++)
          s[n] = __builtin_amdgcn_mfma_f32_16x16x32_bf16(qf[kk], bk[n], s[n], 0, 0, 0);
        __builtin_amdgcn_s_setprio(0);
      }
      // ---- mask (last tile only) + online max + exp (raw-score domain) ----
      const bool needmask = (t == qb);
#pragma unroll
      for (int r = 0; r < 4; r++) {
        const int qg = qw0 + lq * 4 + r;
        float mx = -1e30f;
#pragma unroll
        for (int n = 0; n < 4; n++) {
          float v = s[n][r];
          if (needmask) v = (kv0 + n * 16 + l15 <= qg) ? v : -1e30f;
          s[n][r] = v;
          mx = fmaxf(mx, v);
        }
        mx = fmaxf(mx, __shfl_xor(mx, 1));
        mx = fmaxf(mx, __shfl_xor(mx, 2));
        mx = fmaxf(mx, __shfl_xor(mx, 4));
        mx = fmaxf(mx, __shfl_xor(mx, 8));
        float mn = fmaxf(mrow[r], mx);
        float alpha = exp2f((mrow[r] - mn) * c);
        mrow[r] = mn;
        float mc = mn * c;
#pragma unroll
        for (int n = 0; n < 4; n++)
          s[n][r] = exp2f(fmaf(s[n][r], c, -mc));
        lacc[r] *= alpha;
#pragma unroll
        for (int d = 0; d < 4; d++) oacc[d][r] *= alpha;
      }
      // ---- P -> per-wave LDS bf16 (swizzled); wave-internal only, no barrier ----
#pragma unroll
      for (int r = 0; r < 4; r++) {
        int row = lq * 4 + r;
        int rx = (row & 7) << 4;
#pragma unroll
        for (int n = 0; n < 4; n++)
          Pl[w][row * 64 + ((((n * 16 + l15) * 2) ^ rx) >> 1)] = f2b(s[n][r]);
      }
      // ---- O += P V ; rowsum += P * ones ; V direct from global ----
      s16x8 ap[2];
#pragma unroll
      for (int kk = 0; kk < 2; kk++)
        ap[kk] = *(const s16x8*)&Pl[w][l15 * 64 + (((kk * 64 + lq * 16) ^ swz) >> 1)];
#pragma unroll
      for (int kk = 0; kk < 2; kk++) {
        s16x8 bv[4];
#pragma unroll
        for (int d = 0; d < 4; d++)
          bv[d] = *(const s16x8*)&vbase[(size_t)(d * 16 + l15) * 2048 + kv0 + kk * 32 + lq * 8];
        __builtin_amdgcn_s_setprio(1);
#pragma unroll
        for (int d = 0; d < 4; d++)
          oacc[d] = __builtin_amdgcn_mfma_f32_16x16x32_bf16(ap[kk], bv[d], oacc[d], 0, 0, 0);
        lacc = __builtin_amdgcn_mfma_f32_16x16x32_bf16(ap[kk], vones, lacc, 0, 0, 0);
        __builtin_amdgcn_s_setprio(0);
      }
    }

    // ---- normalize + store ----
#pragma unroll
    for (int d = 0; d < 4; d++) {
      f32x4 o4;
#pragma unroll
      for (int r = 0; r < 4; r++) o4[r] = oacc[d][r] / lacc[r];
#pragma unroll
      for (int r = 0; r < 4; r++) {
        int qg = qw0 + lq * 4 + r;
        attb[(rowbase + qg) * 1024 + h * 64 + d * 16 + l15] = f2b(o4[r]);
      }
    }
  }
}

extern "C" void kernel_launch(void* const* d_in, const int* in_sizes, int n_in,
                              void* d_out, int out_size, void* d_ws, size_t ws_size,
                              hipStream_t stream) {
  const float* x = (const float*)d_in[0];
  const float* wqkv = (const float*)d_in[1];
  const float* wproj = (const float*)d_in[2];
  const float* bproj = (const float*)d_in[3];
  float* out = (float*)d_out;

  unsigned short* xb = (unsigned short*)d_ws;            // 8192*1024
  unsigned short* wqkvb = xb + (size_t)8192 * 1024;      // 3072*1024
  unsigned short* wprojb = wqkvb + (size_t)3072 * 1024;  // 1024*1024
  unsigned short* qkb = wprojb + (size_t)1024 * 1024;    // 8192*2048
  unsigned short* vtb = qkb + (size_t)8192 * 2048;       // 4*16*64*2048
  unsigned short* attb = vtb + (size_t)4 * 16 * 64 * 2048;  // 8192*1024

  cvt_kernel<<<(8192 * 1024 / 4 + 255) / 256, 256, 0, stream>>>(x, xb, 8192 * 1024 / 4);
  cvt_kernel<<<(3072 * 1024 / 4 + 255) / 256, 256, 0, stream>>>(wqkv, wqkvb, 3072 * 1024 / 4);
  cvt_kernel<<<(1024 * 1024 / 4 + 255) / 256, 256, 0, stream>>>(wproj, wprojb, 1024 * 1024 / 4);

  gemm_bt<8192, 3072, 1024, 1>
      <<<dim3(3072 / 128, 8192 / 128), 256, 0, stream>>>(xb, wqkvb, nullptr, qkb, vtb);

  attn_kernel<<<1024, 256, 0, stream>>>(qkb, vtb, attb);

  gemm_bt<8192, 1024, 1024, 2>
      <<<dim3(1024 / 128, 8192 / 128), 256, 0, stream>>>(attb, wprojb, bproj, out, nullptr);
}

// Round 8
// 252.726 us; speedup vs baseline: 2.3713x; 1.4617x over previous
//
#include <hip/hip_runtime.h>
#include <stdint.h>

// B=4, T=2048, C=1024, H=16, HD=64
// qbuf: [B*T][1024] bf16 (Q)
// kf/vf: [B*16+h][32 tiles][8 frag][64 lane][8] bf16 -- MFMA-fragment-linear 8KB tiles
// attb: [B*T][1024] bf16

typedef float f32x4 __attribute__((ext_vector_type(4)));
typedef short s16x8 __attribute__((ext_vector_type(8)));
typedef unsigned short u16x4 __attribute__((ext_vector_type(4)));

typedef __attribute__((address_space(1))) const unsigned int gu32;
typedef __attribute__((address_space(3))) unsigned int lu32;

__device__ __forceinline__ unsigned short f2b(float f) {
  unsigned u = __builtin_bit_cast(unsigned, f);
  u += 0x7fffu + ((u >> 16) & 1u);
  return (unsigned short)(u >> 16);
}

__device__ __forceinline__ void gload16(const void* g, void* l) {
  __builtin_amdgcn_global_load_lds((gu32*)g, (lu32*)l, 16, 0, 0);
}

// ---------------- fp32 -> bf16 conversion ----------------
__global__ __launch_bounds__(256) void cvt_kernel(const float* __restrict__ in,
                                                  unsigned short* __restrict__ out,
                                                  int n4) {
  int i = blockIdx.x * 256 + threadIdx.x;
  if (i < n4) {
    float4 v = reinterpret_cast<const float4*>(in)[i];
    ushort4 o;
    o.x = f2b(v.x); o.y = f2b(v.y); o.z = f2b(v.z); o.w = f2b(v.w);
    reinterpret_cast<ushort4*>(out)[i] = o;
  }
}

// ---------------- GEMM: C = A[M][K] * B[N][K]^T ----------------
// OUTMODE 1: QKV split: Q cols -> qbuf [M][1024]; K cols -> kf tiles; V cols -> vf tiles
// OUTMODE 2: f32 + bias -> C0
template <int M, int N, int K, int OUTMODE>
__global__ __launch_bounds__(256) void gemm_bt(const unsigned short* __restrict__ A,
                                               const unsigned short* __restrict__ B,
                                               const float* __restrict__ bias,
                                               void* __restrict__ C0,
                                               void* __restrict__ C1,
                                               void* __restrict__ C2) {
  __shared__ __align__(16) unsigned short As[128 * 64];
  __shared__ __align__(16) unsigned short Bs[128 * 64];
  const int tid = threadIdx.x;
  const int l = tid & 63, w = tid >> 6;
  const int l15 = l & 15, lq = l >> 4;
  const int wr = w >> 1, wc = w & 1;
  const int m0 = blockIdx.y * 128, n0 = blockIdx.x * 128;
  f32x4 acc[4][4] = {};
  for (int k0 = 0; k0 < K; k0 += 64) {
    __syncthreads();
#pragma unroll
    for (int i = 0; i < 4; i++) {
      int idx = i * 256 + tid;
      gload16(A + (size_t)(m0 + (idx >> 3)) * K + k0 + (idx & 7) * 8, &As[idx * 8]);
    }
#pragma unroll
    for (int i = 0; i < 4; i++) {
      int idx = i * 256 + tid;
      gload16(B + (size_t)(n0 + (idx >> 3)) * K + k0 + (idx & 7) * 8, &Bs[idx * 8]);
    }
    __syncthreads();
#pragma unroll
    for (int kk = 0; kk < 2; kk++) {
      s16x8 af[4], bfv[4];
#pragma unroll
      for (int m = 0; m < 4; m++)
        af[m] = *(const s16x8*)&As[(wr * 64 + m * 16 + l15) * 64 + kk * 32 + lq * 8];
#pragma unroll
      for (int n = 0; n < 4; n++)
        bfv[n] = *(const s16x8*)&Bs[(wc * 64 + n * 16 + l15) * 64 + kk * 32 + lq * 8];
#pragma unroll
      for (int m = 0; m < 4; m++)
#pragma unroll
        for (int n = 0; n < 4; n++)
          acc[m][n] = __builtin_amdgcn_mfma_f32_16x16x32_bf16(af[m], bfv[n], acc[m][n], 0, 0, 0);
    }
  }
  if (OUTMODE == 1) {
    if (n0 < 1024) {
      // Q -> row-major [M][1024]
      unsigned short* q = (unsigned short*)C0;
#pragma unroll
      for (int m = 0; m < 4; m++)
#pragma unroll
        for (int n = 0; n < 4; n++)
#pragma unroll
          for (int r = 0; r < 4; r++) {
            int row = m0 + wr * 64 + m * 16 + lq * 4 + r;
            int col = n0 + wc * 64 + n * 16 + l15;
            q[(size_t)row * 1024 + col] = f2b(acc[m][n][r]);
          }
    } else if (n0 < 2048) {
      // K -> fragment-linear tiles: kf[(bh*32+t)*4096 + f*512 + lane*8 + j]
      // f=(d>>5)*4+(ki>>4), lane=((d>>3)&3)*16+(ki&15), j=d&7
      unsigned short* kf = (unsigned short*)C1;
#pragma unroll
      for (int m = 0; m < 4; m++)
#pragma unroll
        for (int n = 0; n < 4; n++)
#pragma unroll
          for (int r = 0; r < 4; r++) {
            int key = m0 + wr * 64 + m * 16 + lq * 4 + r;
            int col = n0 - 1024 + wc * 64 + n * 16 + l15;  // h*64+d
            int hh = col >> 6, d = col & 63;
            int bb = key >> 11, kt = (key & 2047) >> 6, ki = key & 63;
            int f = (d >> 5) * 4 + (ki >> 4);
            int lane = ((d >> 3) & 3) * 16 + (ki & 15);
            kf[((size_t)((bb * 16 + hh) * 32 + kt)) * 4096 + f * 512 + lane * 8 + (d & 7)] =
                f2b(acc[m][n][r]);
          }
    } else {
      // V -> fragment-linear tiles: vf[(bh*32+t)*4096 + f*512 + lane*8 + j]
      // f=(ki>>5)*4+(d>>4), lane=((ki>>3)&3)*16+(d&15), j=ki&7; pack r (4 keys)
      unsigned short* vf = (unsigned short*)C2;
#pragma unroll
      for (int m = 0; m < 4; m++)
#pragma unroll
        for (int n = 0; n < 4; n++) {
          int row0 = m0 + wr * 64 + m * 16 + lq * 4;  // key base (mult of 4)
          int col = n0 - 2048 + wc * 64 + n * 16 + l15;  // h*64+d
          int hh = col >> 6, d = col & 63;
          int bb = row0 >> 11, q0 = row0 & 2047, kt = q0 >> 6, ki0 = q0 & 63;
          int f = (ki0 >> 5) * 4 + (d >> 4);
          int lane = ((ki0 >> 3) & 3) * 16 + (d & 15);
          u16x4 o;
#pragma unroll
          for (int r = 0; r < 4; r++) o[r] = f2b(acc[m][n][r]);
          *(u16x4*)&vf[((size_t)((bb * 16 + hh) * 32 + kt)) * 4096 + f * 512 + lane * 8 +
                       (ki0 & 7)] = o;
        }
    }
  } else {
#pragma unroll
    for (int m = 0; m < 4; m++)
#pragma unroll
      for (int n = 0; n < 4; n++)
#pragma unroll
        for (int r = 0; r < 4; r++) {
          int row = m0 + wr * 64 + m * 16 + lq * 4 + r;
          int col = n0 + wc * 64 + n * 16 + l15;
          ((float*)C0)[(size_t)row * N + col] = acc[m][n][r] + bias[col];
        }
  }
}

// ---------------- Flash attention (causal), barrier-free, reg-pipelined ----------------
// K/V from fragment-linear 8KB tiles: one contiguous 1KB segment per load instr.
// 1 block = (b, h, pair pi): q-groups 31-pi then pi (64 rows each, 33 tiles total).
// 4 waves x 16 q rows, fully independent (no __syncthreads).
// Register pipeline: preload K/V(0); per tile issue K(t+1) after QK, V(t+1) after PV.
__global__ __launch_bounds__(256, 3) void attn_kernel(const unsigned short* __restrict__ qbuf,
                                                      const unsigned short* __restrict__ kf,
                                                      const unsigned short* __restrict__ vf,
                                                      unsigned short* __restrict__ attb) {
  __shared__ __align__(16) unsigned short Pl[4][16 * 64];  // 8 KB
  const int tid = threadIdx.x, l = tid & 63, w = tid >> 6;
  const int l15 = l & 15, lq = l >> 4;
  // XCD-bijective swizzle: each XCD gets 128 consecutive logical ids = 8 heads x 1 batch.
  const int lbid = (blockIdx.x & 7) * 128 + (blockIdx.x >> 3);
  const int pi = lbid & 15;
  const int h = (lbid >> 4) & 15, b = lbid >> 8;
  const size_t rowbase = (size_t)b * 2048;
  const unsigned short* kbase = kf + (size_t)((b * 16 + h) * 32) * 4096;
  const unsigned short* vbase = vf + (size_t)((b * 16 + h) * 32) * 4096;
  const int loff = l * 8;                    // lane slot within a fragment
  const int swz = (l15 & 7) << 4;            // P read-side XOR (byte units)
  const float c = 0.18033688011112042f;      // 0.125 * log2(e)
  const s16x8 vones = {16256, 16256, 16256, 16256, 16256, 16256, 16256, 16256};  // bf16 1.0

  for (int half = 0; half < 2; half++) {
    const int qb = half ? pi : 31 - pi;      // 64-row q-group index, 0..31
    const int q0 = qb * 64;
    const int qw0 = q0 + w * 16;             // this wave's first q row

    // Q fragments: qf[kk], row = qw0+l15, k = kk*32+lq*8+j
    s16x8 qf[2];
#pragma unroll
    for (int kk = 0; kk < 2; kk++)
      qf[kk] = *(const s16x8*)&qbuf[(rowbase + qw0 + l15) * 1024 + h * 64 + kk * 32 + lq * 8];

    f32x4 oacc[4] = {};
    f32x4 lacc = {};
    float mrow[4] = {-1e30f, -1e30f, -1e30f, -1e30f};

    // preload K(0), V(0) fragments (each load = contiguous 1KB per wave)
    s16x8 bk[2][4], bv[2][4];
#pragma unroll
    for (int kk = 0; kk < 2; kk++)
#pragma unroll
      for (int n = 0; n < 4; n++) {
        bk[kk][n] = *(const s16x8*)&kbase[(kk * 4 + n) * 512 + loff];
        bv[kk][n] = *(const s16x8*)&vbase[(kk * 4 + n) * 512 + loff];
      }

    for (int t = 0; t <= qb; ++t) {
      // ---- S = Q K^T (16 x 64 per wave) ----
      f32x4 s[4];
#pragma unroll
      for (int n = 0; n < 4; n++) s[n] = (f32x4){0.f, 0.f, 0.f, 0.f};
      __builtin_amdgcn_s_setprio(1);
#pragma unroll
      for (int kk = 0; kk < 2; kk++)
#pragma unroll
        for (int n = 0; n < 4; n++)
          s[n] = __builtin_amdgcn_mfma_f32_16x16x32_bf16(qf[kk], bk[kk][n], s[n], 0, 0, 0);
      __builtin_amdgcn_s_setprio(0);
      // ---- prefetch K(t+1) into just-freed regs ----
      if (t < qb) {
        const unsigned short* kt = kbase + (size_t)(t + 1) * 4096;
#pragma unroll
        for (int kk = 0; kk < 2; kk++)
#pragma unroll
          for (int n = 0; n < 4; n++)
            bk[kk][n] = *(const s16x8*)&kt[(kk * 4 + n) * 512 + loff];
      }
      // ---- mask (last tile only) + online max + exp (raw-score domain) ----
      const bool needmask = (t == qb);
#pragma unroll
      for (int r = 0; r < 4; r++) {
        const int qg = qw0 + lq * 4 + r;
        float mx = -1e30f;
#pragma unroll
        for (int n = 0; n < 4; n++) {
          float v = s[n][r];
          if (needmask) v = ((t << 6) + n * 16 + l15 <= qg) ? v : -1e30f;
          s[n][r] = v;
          mx = fmaxf(mx, v);
        }
        mx = fmaxf(mx, __shfl_xor(mx, 1));
        mx = fmaxf(mx, __shfl_xor(mx, 2));
        mx = fmaxf(mx, __shfl_xor(mx, 4));
        mx = fmaxf(mx, __shfl_xor(mx, 8));
        float mn = fmaxf(mrow[r], mx);
        float alpha = exp2f((mrow[r] - mn) * c);
        mrow[r] = mn;
        float mc = mn * c;
#pragma unroll
        for (int n = 0; n < 4; n++)
          s[n][r] = exp2f(fmaf(s[n][r], c, -mc));
        lacc[r] *= alpha;
#pragma unroll
        for (int d = 0; d < 4; d++) oacc[d][r] *= alpha;
      }
      // ---- P -> per-wave LDS bf16 (swizzled); wave-internal, no barrier ----
#pragma unroll
      for (int r = 0; r < 4; r++) {
        int row = lq * 4 + r;
        int rx = (row & 7) << 4;
#pragma unroll
        for (int n = 0; n < 4; n++)
          Pl[w][row * 64 + ((((n * 16 + l15) * 2) ^ rx) >> 1)] = f2b(s[n][r]);
      }
      s16x8 ap[2];
#pragma unroll
      for (int kk = 0; kk < 2; kk++)
        ap[kk] = *(const s16x8*)&Pl[w][l15 * 64 + (((kk * 64 + lq * 16) ^ swz) >> 1)];
      // ---- O += P V ; rowsum += P * ones ----
      __builtin_amdgcn_s_setprio(1);
#pragma unroll
      for (int kk = 0; kk < 2; kk++) {
#pragma unroll
        for (int d = 0; d < 4; d++)
          oacc[d] = __builtin_amdgcn_mfma_f32_16x16x32_bf16(ap[kk], bv[kk][d], oacc[d], 0, 0, 0);
        lacc = __builtin_amdgcn_mfma_f32_16x16x32_bf16(ap[kk], vones, lacc, 0, 0, 0);
      }
      __builtin_amdgcn_s_setprio(0);
      // ---- prefetch V(t+1) ----
      if (t < qb) {
        const unsigned short* vtp = vbase + (size_t)(t + 1) * 4096;
#pragma unroll
        for (int kk = 0; kk < 2; kk++)
#pragma unroll
          for (int n = 0; n < 4; n++)
            bv[kk][n] = *(const s16x8*)&vtp[(kk * 4 + n) * 512 + loff];
      }
    }

    // ---- normalize + store ----
#pragma unroll
    for (int d = 0; d < 4; d++) {
      f32x4 o4;
#pragma unroll
      for (int r = 0; r < 4; r++) o4[r] = oacc[d][r] / lacc[r];
#pragma unroll
      for (int r = 0; r < 4; r++) {
        int qg = qw0 + lq * 4 + r;
        attb[(rowbase + qg) * 1024 + h * 64 + d * 16 + l15] = f2b(o4[r]);
      }
    }
  }
}

extern "C" void kernel_launch(void* const* d_in, const int* in_sizes, int n_in,
                              void* d_out, int out_size, void* d_ws, size_t ws_size,
                              hipStream_t stream) {
  const float* x = (const float*)d_in[0];
  const float* wqkv = (const float*)d_in[1];
  const float* wproj = (const float*)d_in[2];
  const float* bproj = (const float*)d_in[3];
  float* out = (float*)d_out;

  unsigned short* xb = (unsigned short*)d_ws;            // 8192*1024
  unsigned short* wqkvb = xb + (size_t)8192 * 1024;      // 3072*1024
  unsigned short* wprojb = wqkvb + (size_t)3072 * 1024;  // 1024*1024
  unsigned short* qbuf = wprojb + (size_t)1024 * 1024;   // 8192*1024
  unsigned short* kfb = qbuf + (size_t)8192 * 1024;      // 64*32*4096
  unsigned short* vfb = kfb + (size_t)64 * 32 * 4096;    // 64*32*4096
  unsigned short* attb = vfb + (size_t)64 * 32 * 4096;   // 8192*1024

  cvt_kernel<<<(8192 * 1024 / 4 + 255) / 256, 256, 0, stream>>>(x, xb, 8192 * 1024 / 4);
  cvt_kernel<<<(3072 * 1024 / 4 + 255) / 256, 256, 0, stream>>>(wqkv, wqkvb, 3072 * 1024 / 4);
  cvt_kernel<<<(1024 * 1024 / 4 + 255) / 256, 256, 0, stream>>>(wproj, wprojb, 1024 * 1024 / 4);

  gemm_bt<8192, 3072, 1024, 1>
      <<<dim3(3072 / 128, 8192 / 128), 256, 0, stream>>>(xb, wqkvb, nullptr, qbuf, kfb, vfb);

  attn_kernel<<<1024, 256, 0, stream>>>(qbuf, kfb, vfb, attb);

  gemm_bt<8192, 1024, 1024, 2>
      <<<dim3(1024 / 128, 8192 / 128), 256, 0, stream>>>(attb, wprojb, bproj, out, nullptr, nullptr);
}

// Round 10
// 226.073 us; speedup vs baseline: 2.6509x; 1.1179x over previous
//
#include <hip/hip_runtime.h>
#include <stdint.h>

// B=4, T=2048, C=1024, H=16, HD=64
// qbuf: [B*T][1024] bf16 (Q)
// kf: [bh][64 tiles][4 dslice][64 lane][8] bf16  (K as 32x32x16 A-operand frags)
// vf: [bh][64 tiles][4 (dh*2+ks)][64 lane][8] bf16 (V^T as 32x32x16 A-operand frags)
// attb: [B*T][1024] bf16

typedef float f32x4 __attribute__((ext_vector_type(4)));
typedef float f32x16 __attribute__((ext_vector_type(16)));
typedef short s16x8 __attribute__((ext_vector_type(8)));
typedef unsigned short u16x4 __attribute__((ext_vector_type(4)));
typedef unsigned int u32x4 __attribute__((ext_vector_type(4)));

typedef __attribute__((address_space(1))) const unsigned int gu32;
typedef __attribute__((address_space(3))) unsigned int lu32;

__device__ __forceinline__ unsigned short f2b(float f) {
  unsigned u = __builtin_bit_cast(unsigned, f);
  u += 0x7fffu + ((u >> 16) & 1u);
  return (unsigned short)(u >> 16);
}

__device__ __forceinline__ void gload16(const void* g, void* l) {
  __builtin_amdgcn_global_load_lds((gu32*)g, (lu32*)l, 16, 0, 0);
}

__device__ __forceinline__ unsigned cvtpk(float lo, float hi) {
  unsigned r;
  asm("v_cvt_pk_bf16_f32 %0, %1, %2" : "=v"(r) : "v"(lo), "v"(hi));
  return r;
}

// ---------------- fp32 -> bf16 conversion ----------------
__global__ __launch_bounds__(256) void cvt_kernel(const float* __restrict__ in,
                                                  unsigned short* __restrict__ out,
                                                  int n4) {
  int i = blockIdx.x * 256 + threadIdx.x;
  if (i < n4) {
    float4 v = reinterpret_cast<const float4*>(in)[i];
    ushort4 o;
    o.x = f2b(v.x); o.y = f2b(v.y); o.z = f2b(v.z); o.w = f2b(v.w);
    reinterpret_cast<ushort4*>(out)[i] = o;
  }
}

// ---------------- GEMM: C = A[M][K] * B[N][K]^T ----------------
// OUTMODE 1: QKV split: Q -> qbuf [M][1024]; K -> kf frags; V -> vf frags
// OUTMODE 2: f32 + bias -> C0
template <int M, int N, int K, int OUTMODE>
__global__ __launch_bounds__(256) void gemm_bt(const unsigned short* __restrict__ A,
                                               const unsigned short* __restrict__ B,
                                               const float* __restrict__ bias,
                                               void* __restrict__ C0,
                                               void* __restrict__ C1,
                                               void* __restrict__ C2) {
  __shared__ __align__(16) unsigned short As[128 * 64];
  __shared__ __align__(16) unsigned short Bs[128 * 64];
  const int tid = threadIdx.x;
  const int l = tid & 63, w = tid >> 6;
  const int l15 = l & 15, lq = l >> 4;
  const int wr = w >> 1, wc = w & 1;
  const int m0 = blockIdx.y * 128, n0 = blockIdx.x * 128;
  f32x4 acc[4][4] = {};
  for (int k0 = 0; k0 < K; k0 += 64) {
    __syncthreads();
#pragma unroll
    for (int i = 0; i < 4; i++) {
      int idx = i * 256 + tid;
      gload16(A + (size_t)(m0 + (idx >> 3)) * K + k0 + (idx & 7) * 8, &As[idx * 8]);
    }
#pragma unroll
    for (int i = 0; i < 4; i++) {
      int idx = i * 256 + tid;
      gload16(B + (size_t)(n0 + (idx >> 3)) * K + k0 + (idx & 7) * 8, &Bs[idx * 8]);
    }
    __syncthreads();
#pragma unroll
    for (int kk = 0; kk < 2; kk++) {
      s16x8 af[4], bfv[4];
#pragma unroll
      for (int m = 0; m < 4; m++)
        af[m] = *(const s16x8*)&As[(wr * 64 + m * 16 + l15) * 64 + kk * 32 + lq * 8];
#pragma unroll
      for (int n = 0; n < 4; n++)
        bfv[n] = *(const s16x8*)&Bs[(wc * 64 + n * 16 + l15) * 64 + kk * 32 + lq * 8];
#pragma unroll
      for (int m = 0; m < 4; m++)
#pragma unroll
        for (int n = 0; n < 4; n++)
          acc[m][n] = __builtin_amdgcn_mfma_f32_16x16x32_bf16(af[m], bfv[n], acc[m][n], 0, 0, 0);
    }
  }
  if (OUTMODE == 1) {
    if (n0 < 1024) {
      unsigned short* q = (unsigned short*)C0;
#pragma unroll
      for (int m = 0; m < 4; m++)
#pragma unroll
        for (int n = 0; n < 4; n++)
#pragma unroll
          for (int r = 0; r < 4; r++) {
            int row = m0 + wr * 64 + m * 16 + lq * 4 + r;
            int col = n0 + wc * 64 + n * 16 + l15;
            q[(size_t)row * 1024 + col] = f2b(acc[m][n][r]);
          }
    } else if (n0 < 2048) {
      // K frags: kf[(bh*64+t)*2048 + ds*512 + (hid*32+ki)*8 + (d&7)]
      //   = K[key=t*32+ki][d = ds*16 + hid*8 + (d&7)]
      unsigned short* kf = (unsigned short*)C1;
#pragma unroll
      for (int m = 0; m < 4; m++)
#pragma unroll
        for (int n = 0; n < 4; n++)
#pragma unroll
          for (int r = 0; r < 4; r++) {
            int key = m0 + wr * 64 + m * 16 + lq * 4 + r;
            int col = n0 - 1024 + wc * 64 + n * 16 + l15;  // h*64+d
            int hh = col >> 6, d = col & 63;
            int bb = key >> 11, k2 = key & 2047, t = k2 >> 5, ki = k2 & 31;
            int ds = d >> 4, hid = (d >> 3) & 1;
            kf[((size_t)((bb * 16 + hh) * 64 + t)) * 2048 + ds * 512 + (hid * 32 + ki) * 8 +
               (d & 7)] = f2b(acc[m][n][r]);
          }
    } else {
      // V^T frags: vf[(bh*64+t)*2048 + (dh*2+ks)*512 + (hik*32+(d&31))*8 + j]
      //   = V[key=t*32+ks*16+hik*8+j][d]
      unsigned short* vf = (unsigned short*)C2;
#pragma unroll
      for (int m = 0; m < 4; m++)
#pragma unroll
        for (int n = 0; n < 4; n++) {
          int key0 = m0 + wr * 64 + m * 16 + lq * 4;
          int col = n0 - 2048 + wc * 64 + n * 16 + l15;  // h*64+d
          int hh = col >> 6, d = col & 63;
          int bb = key0 >> 11, k2 = key0 & 2047, t = k2 >> 5, ki0 = k2 & 31;
          int ks = ki0 >> 4, hik = (ki0 >> 3) & 1, j0 = ki0 & 7;
          int dh = d >> 5;
          u16x4 o;
#pragma unroll
          for (int r = 0; r < 4; r++) o[r] = f2b(acc[m][n][r]);
          *(u16x4*)&vf[((size_t)((bb * 16 + hh) * 64 + t)) * 2048 + (dh * 2 + ks) * 512 +
                       (hik * 32 + (d & 31)) * 8 + j0] = o;
        }
    }
  } else {
#pragma unroll
    for (int m = 0; m < 4; m++)
#pragma unroll
      for (int n = 0; n < 4; n++)
#pragma unroll
        for (int r = 0; r < 4; r++) {
          int row = m0 + wr * 64 + m * 16 + lq * 4 + r;
          int col = n0 + wc * 64 + n * 16 + l15;
          ((float*)C0)[(size_t)row * N + col] = acc[m][n][r] + bias[col];
        }
  }
}

// ---------------- Flash attention (causal), swapped-operand, zero-LDS ----------------
// S^T = mfma32x32x16(K, Q): lane owns q=lane&31; keys in regs (crow mapping).
// Softmax fully in-register: lane-local max/sum + shfl_xor(32) cross-half combine.
// P -> PV B-operand via cvt_pk + shfl_xor(32) + per-half select.
// O^T = mfma(V^T, P): q stays lane-local -> rescale lane-local. No LDS, no barriers.
// 1 block = (b, h, 128 q rows), 4 waves x 32 q rows; KV tiles of 32.
__global__ __launch_bounds__(256, 3) void attn_kernel(const unsigned short* __restrict__ qbuf,
                                                      const unsigned short* __restrict__ kf,
                                                      const unsigned short* __restrict__ vf,
                                                      unsigned short* __restrict__ attb) {
  const int tid = threadIdx.x, l = tid & 63, w = tid >> 6;
  const int q32 = l & 31, hi = l >> 5;
  // XCD-bijective swizzle: each XCD gets 128 consecutive logical ids = 8 heads x 1 batch.
  const int lbid = (blockIdx.x & 7) * 128 + (blockIdx.x >> 3);
  const int g = 15 - (lbid & 15);  // descending: long blocks first
  const int h = (lbid >> 4) & 15, b = lbid >> 8;
  const size_t rowbase = (size_t)b * 2048;
  const unsigned short* kbase = kf + (size_t)((b * 16 + h) * 64) * 2048;
  const unsigned short* vbase = vf + (size_t)((b * 16 + h) * 64) * 2048;
  const int loff = l * 8;
  const float c = 0.18033688011112042f;  // 0.125 * log2(e)

  const int qw0 = g * 128 + w * 32;  // this wave's first q row
  const int tl = qw0 >> 5;           // last (diagonal) 32-key tile

  // Q fragments (B-operand): qf[ds]: Q[q=q32][d = ds*16 + hi*8 + j]
  s16x8 qf[4];
#pragma unroll
  for (int ds = 0; ds < 4; ds++)
    qf[ds] = *(const s16x8*)&qbuf[(rowbase + qw0 + q32) * 1024 + h * 64 + ds * 16 + hi * 8];

  f32x16 oacc0 = {}, oacc1 = {};  // O^T: lane q=q32; d = dh*32 + crow(reg,hi)
  float lacc = 0.f, mrow = -1e30f;

  // preload K(0), V(0) fragments (each = contiguous 1KB segment per wave)
  s16x8 bk[4], bv[4];
#pragma unroll
  for (int f = 0; f < 4; f++) {
    bk[f] = *(const s16x8*)&kbase[f * 512 + loff];
    bv[f] = *(const s16x8*)&vbase[f * 512 + loff];
  }

  for (int t = 0; t <= tl; ++t) {
    // ---- S^T = K·Q^T (32 keys x 32 q per wave) ----
    f32x16 st = {};
    __builtin_amdgcn_s_setprio(1);
#pragma unroll
    for (int ds = 0; ds < 4; ds++)
      st = __builtin_amdgcn_mfma_f32_32x32x16_bf16(bk[ds], qf[ds], st, 0, 0, 0);
    __builtin_amdgcn_s_setprio(0);
    // ---- prefetch K(t+1) ----
    if (t < tl) {
      const unsigned short* kt = kbase + (size_t)(t + 1) * 2048;
#pragma unroll
      for (int f = 0; f < 4; f++) bk[f] = *(const s16x8*)&kt[f * 512 + loff];
    }
    // ---- causal mask (diagonal tile only): key_local = creg + 4*hi <= q32 ----
    if (t == tl) {
#pragma unroll
      for (int reg = 0; reg < 16; reg++) {
        const int creg = (reg & 3) + 8 * (reg >> 2);
        st[reg] = (creg + 4 * hi <= q32) ? st[reg] : -1e30f;
      }
    }
    // ---- lane-local max over 16 regs + cross-half combine (shfl) ----
    float mx = st[0];
#pragma unroll
    for (int reg = 1; reg < 16; reg++) mx = fmaxf(mx, st[reg]);
    mx = fmaxf(mx, __shfl_xor(mx, 32));
    // ---- defer-max (T13): skip rescale when growth bounded ----
    if (!__all(mx <= mrow + 48.0f)) {
      float mn = fmaxf(mrow, mx);
      float alpha = exp2f((mrow - mn) * c);
      mrow = mn;
      lacc *= alpha;
#pragma unroll
      for (int reg = 0; reg < 16; reg++) { oacc0[reg] *= alpha; oacc1[reg] *= alpha; }
    }
    // ---- exp (raw domain, scale fused) + lane-local sum + combine ----
    const float mc = mrow * c;
    float ssum = 0.f;
#pragma unroll
    for (int reg = 0; reg < 16; reg++) {
      float p = exp2f(fmaf(st[reg], c, -mc));
      st[reg] = p;
      ssum += p;
    }
    ssum += __shfl_xor(ssum, 32);
    lacc += ssum;
    // ---- pack P -> PV B-operand frags (cvt_pk + shfl_xor + per-half select) ----
    s16x8 pa[2];
#pragma unroll
    for (int ks = 0; ks < 2; ks++) {
      const int bq = ks * 8;
      unsigned a0 = cvtpk(st[bq + 0], st[bq + 1]);
      unsigned a1 = cvtpk(st[bq + 2], st[bq + 3]);
      unsigned b0 = cvtpk(st[bq + 4], st[bq + 5]);
      unsigned b1 = cvtpk(st[bq + 6], st[bq + 7]);
      unsigned xa0 = (unsigned)__shfl_xor((int)a0, 32);
      unsigned xa1 = (unsigned)__shfl_xor((int)a1, 32);
      unsigned xb0 = (unsigned)__shfl_xor((int)b0, 32);
      unsigned xb1 = (unsigned)__shfl_xor((int)b1, 32);
      unsigned w0 = hi ? xb0 : a0;  // j=0,1
      unsigned w1 = hi ? xb1 : a1;  // j=2,3
      unsigned w2 = hi ? b0 : xa0;  // j=4,5
      unsigned w3 = hi ? b1 : xa1;  // j=6,7
      pa[ks] = __builtin_bit_cast(s16x8, (u32x4){w0, w1, w2, w3});
    }
    // ---- O^T += V^T · P ----
    __builtin_amdgcn_s_setprio(1);
#pragma unroll
    for (int ks = 0; ks < 2; ks++) {
      oacc0 = __builtin_amdgcn_mfma_f32_32x32x16_bf16(bv[0 * 2 + ks], pa[ks], oacc0, 0, 0, 0);
      oacc1 = __builtin_amdgcn_mfma_f32_32x32x16_bf16(bv[1 * 2 + ks], pa[ks], oacc1, 0, 0, 0);
    }
    __builtin_amdgcn_s_setprio(0);
    // ---- prefetch V(t+1) ----
    if (t < tl) {
      const unsigned short* vtp = vbase + (size_t)(t + 1) * 2048;
#pragma unroll
      for (int f = 0; f < 4; f++) bv[f] = *(const s16x8*)&vtp[f * 512 + loff];
    }
  }

  // ---- normalize + store: lane writes its q-row, 8x u16x4 chunks ----
  const float rinv = 1.0f / lacc;
  unsigned short* orow = attb + (rowbase + qw0 + q32) * 1024 + h * 64;
#pragma unroll
  for (int rg = 0; rg < 4; rg++) {
    u16x4 o0, o1;
#pragma unroll
    for (int r = 0; r < 4; r++) {
      o0[r] = f2b(oacc0[rg * 4 + r] * rinv);
      o1[r] = f2b(oacc1[rg * 4 + r] * rinv);
    }
    *(u16x4*)&orow[rg * 8 + hi * 4] = o0;
    *(u16x4*)&orow[32 + rg * 8 + hi * 4] = o1;
  }
}

extern "C" void kernel_launch(void* const* d_in, const int* in_sizes, int n_in,
                              void* d_out, int out_size, void* d_ws, size_t ws_size,
                              hipStream_t stream) {
  const float* x = (const float*)d_in[0];
  const float* wqkv = (const float*)d_in[1];
  const float* wproj = (const float*)d_in[2];
  const float* bproj = (const float*)d_in[3];
  float* out = (float*)d_out;

  unsigned short* xb = (unsigned short*)d_ws;            // 8192*1024
  unsigned short* wqkvb = xb + (size_t)8192 * 1024;      // 3072*1024
  unsigned short* wprojb = wqkvb + (size_t)3072 * 1024;  // 1024*1024
  unsigned short* qbuf = wprojb + (size_t)1024 * 1024;   // 8192*1024
  unsigned short* kfb = qbuf + (size_t)8192 * 1024;      // 64*64*2048
  unsigned short* vfb = kfb + (size_t)64 * 64 * 2048;    // 64*64*2048
  unsigned short* attb = vfb + (size_t)64 * 64 * 2048;   // 8192*1024

  cvt_kernel<<<(8192 * 1024 / 4 + 255) / 256, 256, 0, stream>>>(x, xb, 8192 * 1024 / 4);
  cvt_kernel<<<(3072 * 1024 / 4 + 255) / 256, 256, 0, stream>>>(wqkv, wqkvb, 3072 * 1024 / 4);
  cvt_kernel<<<(1024 * 1024 / 4 + 255) / 256, 256, 0, stream>>>(wproj, wprojb, 1024 * 1024 / 4);

  gemm_bt<8192, 3072, 1024, 1>
      <<<dim3(3072 / 128, 8192 / 128), 256, 0, stream>>>(xb, wqkvb, nullptr, qbuf, kfb, vfb);

  attn_kernel<<<1024, 256, 0, stream>>>(qbuf, kfb, vfb, attb);

  gemm_bt<8192, 1024, 1024, 2>
      <<<dim3(1024 / 128, 8192 / 128), 256, 0, stream>>>(attb, wprojb, bproj, out, nullptr, nullptr);
}

// Round 12
// 201.519 us; speedup vs baseline: 2.9739x; 1.1218x over previous
//
#include <hip/hip_runtime.h>
#include <stdint.h>

// B=4, T=2048, C=1024, H=16, HD=64
// qbuf: [B*T][1024] bf16 (Q)
// kf: [bh][64 tiles][4 dslice][64 lane][8] bf16  (K as 32x32x16 A-operand frags)
// vf: [bh][64 tiles][4 (dh*2+ks)][64 lane][8] bf16 (V^T as 32x32x16 A-operand frags)
// attb: [B*T][1024] bf16

typedef float f32x4 __attribute__((ext_vector_type(4)));
typedef float f32x16 __attribute__((ext_vector_type(16)));
typedef short s16x8 __attribute__((ext_vector_type(8)));
typedef unsigned short u16x4 __attribute__((ext_vector_type(4)));
typedef unsigned int u32x4 __attribute__((ext_vector_type(4)));

typedef __attribute__((address_space(1))) const unsigned int gu32;
typedef __attribute__((address_space(3))) unsigned int lu32;

__device__ __forceinline__ unsigned short f2b(float f) {
  unsigned u = __builtin_bit_cast(unsigned, f);
  u += 0x7fffu + ((u >> 16) & 1u);
  return (unsigned short)(u >> 16);
}

__device__ __forceinline__ void gload16(const void* g, void* l) {
  __builtin_amdgcn_global_load_lds((gu32*)g, (lu32*)l, 16, 0, 0);
}

__device__ __forceinline__ unsigned cvtpk(float lo, float hi) {
  unsigned r;
  asm("v_cvt_pk_bf16_f32 %0, %1, %2" : "=v"(r) : "v"(lo), "v"(hi));
  return r;
}

// ---------------- fp32 -> bf16 conversion ----------------
__global__ __launch_bounds__(256) void cvt_kernel(const float* __restrict__ in,
                                                  unsigned short* __restrict__ out,
                                                  int n4) {
  int i = blockIdx.x * 256 + threadIdx.x;
  if (i < n4) {
    float4 v = reinterpret_cast<const float4*>(in)[i];
    ushort4 o;
    o.x = f2b(v.x); o.y = f2b(v.y); o.z = f2b(v.z); o.w = f2b(v.w);
    reinterpret_cast<ushort4*>(out)[i] = o;
  }
}

// ---------------- GEMM: C = A[M][K] * B[N][K]^T ----------------
// 1D grid, XCD-bijective swizzle, column-major (n-major per XCD) block order.
// OUTMODE 1: QKV split: Q -> qbuf [M][1024]; K -> kf frags; V -> vf frags
// OUTMODE 2: f32 + bias -> C0
template <int M, int N, int K, int OUTMODE>
__global__ __launch_bounds__(256) void gemm_bt(const unsigned short* __restrict__ A,
                                               const unsigned short* __restrict__ B,
                                               const float* __restrict__ bias,
                                               void* __restrict__ C0,
                                               void* __restrict__ C1,
                                               void* __restrict__ C2) {
  __shared__ __align__(16) unsigned short As[128 * 64];
  __shared__ __align__(16) unsigned short Bs[128 * 64];
  const int tid = threadIdx.x;
  const int l = tid & 63, w = tid >> 6;
  const int l15 = l & 15, lq = l >> 4;
  const int wr = w >> 1, wc = w & 1;
  // XCD swizzle (grid % 8 == 0): each XCD gets nwg/8 consecutive logical ids,
  // column-major: m fastest -> few B-panels stay L2-resident per XCD.
  const int nwg = (M / 128) * (N / 128);
  const int wg = (blockIdx.x & 7) * (nwg >> 3) + (blockIdx.x >> 3);
  const int m0 = (wg % (M / 128)) * 128, n0 = (wg / (M / 128)) * 128;
  f32x4 acc[4][4] = {};
  for (int k0 = 0; k0 < K; k0 += 64) {
    __syncthreads();
#pragma unroll
    for (int i = 0; i < 4; i++) {
      int idx = i * 256 + tid;
      gload16(A + (size_t)(m0 + (idx >> 3)) * K + k0 + (idx & 7) * 8, &As[idx * 8]);
    }
#pragma unroll
    for (int i = 0; i < 4; i++) {
      int idx = i * 256 + tid;
      gload16(B + (size_t)(n0 + (idx >> 3)) * K + k0 + (idx & 7) * 8, &Bs[idx * 8]);
    }
    __syncthreads();
#pragma unroll
    for (int kk = 0; kk < 2; kk++) {
      s16x8 af[4], bfv[4];
#pragma unroll
      for (int m = 0; m < 4; m++)
        af[m] = *(const s16x8*)&As[(wr * 64 + m * 16 + l15) * 64 + kk * 32 + lq * 8];
#pragma unroll
      for (int n = 0; n < 4; n++)
        bfv[n] = *(const s16x8*)&Bs[(wc * 64 + n * 16 + l15) * 64 + kk * 32 + lq * 8];
#pragma unroll
      for (int m = 0; m < 4; m++)
#pragma unroll
        for (int n = 0; n < 4; n++)
          acc[m][n] = __builtin_amdgcn_mfma_f32_16x16x32_bf16(af[m], bfv[n], acc[m][n], 0, 0, 0);
    }
  }
  if (OUTMODE == 1) {
    if (n0 < 1024) {
      unsigned short* q = (unsigned short*)C0;
#pragma unroll
      for (int m = 0; m < 4; m++)
#pragma unroll
        for (int n = 0; n < 4; n++)
#pragma unroll
          for (int r = 0; r < 4; r++) {
            int row = m0 + wr * 64 + m * 16 + lq * 4 + r;
            int col = n0 + wc * 64 + n * 16 + l15;
            q[(size_t)row * 1024 + col] = f2b(acc[m][n][r]);
          }
    } else if (n0 < 2048) {
      // K frags: kf[(bh*64+t)*2048 + ds*512 + (hid*32+ki)*8 + (d&7)]
      //   = K[key=t*32+ki][d = ds*16 + hid*8 + (d&7)]
      unsigned short* kf = (unsigned short*)C1;
#pragma unroll
      for (int m = 0; m < 4; m++)
#pragma unroll
        for (int n = 0; n < 4; n++)
#pragma unroll
          for (int r = 0; r < 4; r++) {
            int key = m0 + wr * 64 + m * 16 + lq * 4 + r;
            int col = n0 - 1024 + wc * 64 + n * 16 + l15;  // h*64+d
            int hh = col >> 6, d = col & 63;
            int bb = key >> 11, k2 = key & 2047, t = k2 >> 5, ki = k2 & 31;
            int ds = d >> 4, hid = (d >> 3) & 1;
            kf[((size_t)((bb * 16 + hh) * 64 + t)) * 2048 + ds * 512 + (hid * 32 + ki) * 8 +
               (d & 7)] = f2b(acc[m][n][r]);
          }
    } else {
      // V^T frags: vf[(bh*64+t)*2048 + (dh*2+ks)*512 + (hik*32+(d&31))*8 + j]
      //   = V[key=t*32+ks*16+hik*8+j][d]
      unsigned short* vf = (unsigned short*)C2;
#pragma unroll
      for (int m = 0; m < 4; m++)
#pragma unroll
        for (int n = 0; n < 4; n++) {
          int key0 = m0 + wr * 64 + m * 16 + lq * 4;
          int col = n0 - 2048 + wc * 64 + n * 16 + l15;  // h*64+d
          int hh = col >> 6, d = col & 63;
          int bb = key0 >> 11, k2 = key0 & 2047, t = k2 >> 5, ki0 = k2 & 31;
          int ks = ki0 >> 4, hik = (ki0 >> 3) & 1, j0 = ki0 & 7;
          int dh = d >> 5;
          u16x4 o;
#pragma unroll
          for (int r = 0; r < 4; r++) o[r] = f2b(acc[m][n][r]);
          *(u16x4*)&vf[((size_t)((bb * 16 + hh) * 64 + t)) * 2048 + (dh * 2 + ks) * 512 +
                       (hik * 32 + (d & 31)) * 8 + j0] = o;
        }
    }
  } else {
#pragma unroll
    for (int m = 0; m < 4; m++)
#pragma unroll
      for (int n = 0; n < 4; n++)
#pragma unroll
        for (int r = 0; r < 4; r++) {
          int row = m0 + wr * 64 + m * 16 + lq * 4 + r;
          int col = n0 + wc * 64 + n * 16 + l15;
          ((float*)C0)[(size_t)row * N + col] = acc[m][n][r] + bias[col];
        }
  }
}

// ---------------- Flash attention (causal), swapped-operand, zero-LDS, paired ----------------
// S^T = mfma32x32x16(K, Q): lane owns q=lane&31; softmax in-register (shfl_xor(32)).
// P -> PV B-operand via cvt_pk + shfl_xor(32) + per-half select. O^T = mfma(V^T, P).
// 1 block = (b, h, pair pi): q-groups gA=15-pi then gB=pi (128 rows each) ->
// per-wave work = 62+2w tiles, uniform. Grid 512. No LDS, no barriers.
__global__ __launch_bounds__(256, 3) void attn_kernel(const unsigned short* __restrict__ qbuf,
                                                      const unsigned short* __restrict__ kf,
                                                      const unsigned short* __restrict__ vf,
                                                      unsigned short* __restrict__ attb) {
  const int tid = threadIdx.x, l = tid & 63, w = tid >> 6;
  const int q32 = l & 31, hi = l >> 5;
  // XCD-bijective swizzle: 512 blocks, each XCD gets 64 consecutive logical ids
  // = 8 pairs x 8 heads x 1 batch -> K/V working set 4 MB = its L2.
  const int lbid = (blockIdx.x & 7) * 64 + (blockIdx.x >> 3);
  const int pi = lbid & 7;
  const int h = (lbid >> 3) & 15, b = lbid >> 7;
  const size_t rowbase = (size_t)b * 2048;
  const unsigned short* kbase = kf + (size_t)((b * 16 + h) * 64) * 2048;
  const unsigned short* vbase = vf + (size_t)((b * 16 + h) * 64) * 2048;
  const int loff = l * 8;
  const float c = 0.18033688011112042f;  // 0.125 * log2(e)

  for (int half = 0; half < 2; half++) {
    const int g = half ? pi : 15 - pi;  // 128-row q-group, 0..15
    const int qw0 = g * 128 + w * 32;   // this wave's first q row
    const int tl = qw0 >> 5;            // last (diagonal) 32-key tile

    // Q fragments (B-operand): qf[ds]: Q[q=q32][d = ds*16 + hi*8 + j]
    s16x8 qf[4];
#pragma unroll
    for (int ds = 0; ds < 4; ds++)
      qf[ds] = *(const s16x8*)&qbuf[(rowbase + qw0 + q32) * 1024 + h * 64 + ds * 16 + hi * 8];

    f32x16 oacc0 = {}, oacc1 = {};  // O^T: lane q=q32; d = dh*32 + crow(reg,hi)
    float lacc = 0.f, mrow = -1e30f;

    // preload K(0), V(0) fragments (each = contiguous 1KB segment per wave)
    s16x8 bk[4], bv[4];
#pragma unroll
    for (int f = 0; f < 4; f++) {
      bk[f] = *(const s16x8*)&kbase[f * 512 + loff];
      bv[f] = *(const s16x8*)&vbase[f * 512 + loff];
    }

    for (int t = 0; t <= tl; ++t) {
      // ---- S^T = K·Q^T (32 keys x 32 q per wave) ----
      f32x16 st = {};
      __builtin_amdgcn_s_setprio(1);
#pragma unroll
      for (int ds = 0; ds < 4; ds++)
        st = __builtin_amdgcn_mfma_f32_32x32x16_bf16(bk[ds], qf[ds], st, 0, 0, 0);
      __builtin_amdgcn_s_setprio(0);
      // ---- prefetch K(t+1) (t=tl loads tile 0 for the next half: harmless) ----
      {
        const int tn = (t < tl) ? t + 1 : 0;
        const unsigned short* kt = kbase + (size_t)tn * 2048;
#pragma unroll
        for (int f = 0; f < 4; f++) bk[f] = *(const s16x8*)&kt[f * 512 + loff];
      }
      // ---- causal mask (diagonal tile only): key_local = creg + 4*hi <= q32 ----
      if (t == tl) {
#pragma unroll
        for (int reg = 0; reg < 16; reg++) {
          const int creg = (reg & 3) + 8 * (reg >> 2);
          st[reg] = (creg + 4 * hi <= q32) ? st[reg] : -1e30f;
        }
      }
      // ---- lane-local max over 16 regs + cross-half combine (shfl) ----
      float mx = st[0];
#pragma unroll
      for (int reg = 1; reg < 16; reg++) mx = fmaxf(mx, st[reg]);
      mx = fmaxf(mx, __shfl_xor(mx, 32));
      // ---- defer-max (T13): skip rescale when growth bounded ----
      if (!__all(mx <= mrow + 48.0f)) {
        float mn = fmaxf(mrow, mx);
        float alpha = exp2f((mrow - mn) * c);
        mrow = mn;
        lacc *= alpha;
#pragma unroll
        for (int reg = 0; reg < 16; reg++) { oacc0[reg] *= alpha; oacc1[reg] *= alpha; }
      }
      // ---- exp (raw domain, scale fused) + lane-local sum + combine ----
      const float mc = mrow * c;
      float ssum = 0.f;
#pragma unroll
      for (int reg = 0; reg < 16; reg++) {
        float p = exp2f(fmaf(st[reg], c, -mc));
        st[reg] = p;
        ssum += p;
      }
      ssum += __shfl_xor(ssum, 32);
      lacc += ssum;
      // ---- pack P -> PV B-operand frags (cvt_pk + shfl_xor + per-half select) ----
      s16x8 pa[2];
#pragma unroll
      for (int ks = 0; ks < 2; ks++) {
        const int bq = ks * 8;
        unsigned a0 = cvtpk(st[bq + 0], st[bq + 1]);
        unsigned a1 = cvtpk(st[bq + 2], st[bq + 3]);
        unsigned b0 = cvtpk(st[bq + 4], st[bq + 5]);
        unsigned b1 = cvtpk(st[bq + 6], st[bq + 7]);
        unsigned xa0 = (unsigned)__shfl_xor((int)a0, 32);
        unsigned xa1 = (unsigned)__shfl_xor((int)a1, 32);
        unsigned xb0 = (unsigned)__shfl_xor((int)b0, 32);
        unsigned xb1 = (unsigned)__shfl_xor((int)b1, 32);
        unsigned w0 = hi ? xb0 : a0;  // j=0,1
        unsigned w1 = hi ? xb1 : a1;  // j=2,3
        unsigned w2 = hi ? b0 : xa0;  // j=4,5
        unsigned w3 = hi ? b1 : xa1;  // j=6,7
        pa[ks] = __builtin_bit_cast(s16x8, (u32x4){w0, w1, w2, w3});
      }
      // ---- O^T += V^T · P ----
      __builtin_amdgcn_s_setprio(1);
#pragma unroll
      for (int ks = 0; ks < 2; ks++) {
        oacc0 = __builtin_amdgcn_mfma_f32_32x32x16_bf16(bv[0 * 2 + ks], pa[ks], oacc0, 0, 0, 0);
        oacc1 = __builtin_amdgcn_mfma_f32_32x32x16_bf16(bv[1 * 2 + ks], pa[ks], oacc1, 0, 0, 0);
      }
      __builtin_amdgcn_s_setprio(0);
      // ---- prefetch V(t+1) (or tile 0 for next half) ----
      {
        const int tn = (t < tl) ? t + 1 : 0;
        const unsigned short* vtp = vbase + (size_t)tn * 2048;
#pragma unroll
        for (int f = 0; f < 4; f++) bv[f] = *(const s16x8*)&vtp[f * 512 + loff];
      }
    }

    // ---- normalize + store: lane writes its q-row, 8x u16x4 chunks ----
    const float rinv = 1.0f / lacc;
    unsigned short* orow = attb + (rowbase + qw0 + q32) * 1024 + h * 64;
#pragma unroll
    for (int rg = 0; rg < 4; rg++) {
      u16x4 o0, o1;
#pragma unroll
      for (int r = 0; r < 4; r++) {
        o0[r] = f2b(oacc0[rg * 4 + r] * rinv);
        o1[r] = f2b(oacc1[rg * 4 + r] * rinv);
      }
      *(u16x4*)&orow[rg * 8 + hi * 4] = o0;
      *(u16x4*)&orow[32 + rg * 8 + hi * 4] = o1;
    }
  }
}

extern "C" void kernel_launch(void* const* d_in, const int* in_sizes, int n_in,
                              void* d_out, int out_size, void* d_ws, size_t ws_size,
                              hipStream_t stream) {
  const float* x = (const float*)d_in[0];
  const float* wqkv = (const float*)d_in[1];
  const float* wproj = (const float*)d_in[2];
  const float* bproj = (const float*)d_in[3];
  float* out = (float*)d_out;

  unsigned short* xb = (unsigned short*)d_ws;            // 8192*1024
  unsigned short* wqkvb = xb + (size_t)8192 * 1024;      // 3072*1024
  unsigned short* wprojb = wqkvb + (size_t)3072 * 1024;  // 1024*1024
  unsigned short* qbuf = wprojb + (size_t)1024 * 1024;   // 8192*1024
  unsigned short* kfb = qbuf + (size_t)8192 * 1024;      // 64*64*2048
  unsigned short* vfb = kfb + (size_t)64 * 64 * 2048;    // 64*64*2048
  unsigned short* attb = vfb + (size_t)64 * 64 * 2048;   // 8192*1024

  cvt_kernel<<<(8192 * 1024 / 4 + 255) / 256, 256, 0, stream>>>(x, xb, 8192 * 1024 / 4);
  cvt_kernel<<<(3072 * 1024 / 4 + 255) / 256, 256, 0, stream>>>(wqkv, wqkvb, 3072 * 1024 / 4);
  cvt_kernel<<<(1024 * 1024 / 4 + 255) / 256, 256, 0, stream>>>(wproj, wprojb, 1024 * 1024 / 4);

  gemm_bt<8192, 3072, 1024, 1>
      <<<(8192 / 128) * (3072 / 128), 256, 0, stream>>>(xb, wqkvb, nullptr, qbuf, kfb, vfb);

  attn_kernel<<<512, 256, 0, stream>>>(qbuf, kfb, vfb, attb);

  gemm_bt<8192, 1024, 1024, 2>
      <<<(8192 / 128) * (1024 / 128), 256, 0, stream>>>(attb, wprojb, bproj, out, nullptr, nullptr);
}